// Round 4
// baseline (71.670 us; speedup 1.0000x reference)
//
#include <hip/hip_runtime.h>
#include <math.h>

#define BB 4
#define LL 512
#define DD 128
#define TQ 4                 // queries per block
#define NROW (TQ + 2)        // 6 staged x rows
#define NACC (NROW + TQ)     // 10 GEMV outputs: 0..5 = k rows, 6..9 = q rows
#define NSP 8                // part slices after in-wave fold (16 ks -> 8)
#define EPSV 1e-8f

__device__ __forceinline__ float fast_tanh(float v) {
    float e = __expf(2.0f * v);
    return 1.0f - 2.0f / (e + 1.0f);
}

__global__ __launch_bounds__(512, 4) void additive_emission_kernel(
    const float* __restrict__ x,   // [B,L,D]
    const float* __restrict__ Wt,  // [D,D] row-major [d_in][d_out]
    const float* __restrict__ Wx,  // [D,D]
    const float* __restrict__ Wa,  // [D]
    const float* __restrict__ bh,  // [D]
    const float* __restrict__ ba,  // [1] (cancels in softmax)
    float* __restrict__ out)       // [B,L,D]
{
    __shared__ float xs[NROW][DD];
    __shared__ float part[NSP][NACC][DD];   // 40 KB
    __shared__ float shbh[DD];
    __shared__ float shwa[DD];
    __shared__ float score[TQ * 3];

    const int t = threadIdx.x;
    const int c4 = t & 31;            // float4 column group: cols [c4*4, c4*4+4)
    const int ks = t >> 5;            // 0..15, k-range [ks*8, ks*8+8)
    const int k0 = ks * 8;
    const int wv = t >> 6;            // wave 0..7
    const int lane = t & 63;
    const int b = blockIdx.x >> 7;
    const int tile = blockIdx.x & 127;
    const int i0 = tile * TQ;
    const int jlo = i0 - 1;

    // ---- half-1 weight loads (k0..k0+3): coalesced dwordx4, overlap staging ----
    float4 wt1[4], wx1[4];
    #pragma unroll
    for (int kk = 0; kk < 4; ++kk) {
        wt1[kk] = ((const float4*)(Wt + (size_t)(k0 + kk) * DD))[c4];
        wx1[kk] = ((const float4*)(Wx + (size_t)(k0 + kk) * DD))[c4];
    }

    if (t < DD) { shbh[t] = bh[t]; shwa[t] = Wa[t]; }
    if (t < NROW * (DD / 4)) {        // 192 threads stage 6 x rows as float4
        int r = t >> 5, cc4 = t & 31;
        int j = jlo + r;
        float4 v = make_float4(0.f, 0.f, 0.f, 0.f);
        if (j >= 0 && j < LL)
            v = ((const float4*)x)[(size_t)(b * LL + j) * (DD / 4) + cc4];
        ((float4*)xs[r])[cc4] = v;
    }
    __syncthreads();

    // ---- half-2 weight loads issued now; latency overlaps half-1 FMAs ----
    float4 wt2[4], wx2[4];
    #pragma unroll
    for (int kk = 0; kk < 4; ++kk) {
        wt2[kk] = ((const float4*)(Wt + (size_t)(k0 + 4 + kk) * DD))[c4];
        wx2[kk] = ((const float4*)(Wx + (size_t)(k0 + 4 + kk) * DD))[c4];
    }

    float4 acck[NROW], accq[TQ];
    #pragma unroll
    for (int r = 0; r < NROW; ++r) acck[r] = make_float4(0.f, 0.f, 0.f, 0.f);
    #pragma unroll
    for (int qi = 0; qi < TQ; ++qi) accq[qi] = make_float4(0.f, 0.f, 0.f, 0.f);

    #pragma unroll
    for (int h = 0; h < 2; ++h) {
        const int kb4 = (k0 >> 2) + h;          // float4 index of this k-half
        float xq[NROW][4];
        #pragma unroll
        for (int r = 0; r < NROW; ++r) {        // ds_read_b128, 2-addr broadcast
            float4 v = ((const float4*)xs[r])[kb4];
            xq[r][0] = v.x; xq[r][1] = v.y; xq[r][2] = v.z; xq[r][3] = v.w;
        }
        #pragma unroll
        for (int kk = 0; kk < 4; ++kk) {
            float4 wt = h ? wt2[kk] : wt1[kk];
            float4 wx = h ? wx2[kk] : wx1[kk];
            #pragma unroll
            for (int r = 0; r < NROW; ++r) {
                acck[r].x += xq[r][kk] * wx.x;
                acck[r].y += xq[r][kk] * wx.y;
                acck[r].z += xq[r][kk] * wx.z;
                acck[r].w += xq[r][kk] * wx.w;
            }
            #pragma unroll
            for (int qi = 0; qi < TQ; ++qi) {
                accq[qi].x += xq[qi + 1][kk] * wt.x;
                accq[qi].y += xq[qi + 1][kk] * wt.y;
                accq[qi].z += xq[qi + 1][kk] * wt.z;
                accq[qi].w += xq[qi + 1][kk] * wt.w;
            }
        }
    }

    // ---- fold ks-pairs in-wave (lane l <-> l+32 share c4), write part[wave] ----
    #pragma unroll
    for (int r = 0; r < NROW; ++r) {
        acck[r].x += __shfl_xor(acck[r].x, 32, 64);
        acck[r].y += __shfl_xor(acck[r].y, 32, 64);
        acck[r].z += __shfl_xor(acck[r].z, 32, 64);
        acck[r].w += __shfl_xor(acck[r].w, 32, 64);
    }
    #pragma unroll
    for (int qi = 0; qi < TQ; ++qi) {
        accq[qi].x += __shfl_xor(accq[qi].x, 32, 64);
        accq[qi].y += __shfl_xor(accq[qi].y, 32, 64);
        accq[qi].z += __shfl_xor(accq[qi].z, 32, 64);
        accq[qi].w += __shfl_xor(accq[qi].w, 32, 64);
    }
    if (lane < 32) {
        #pragma unroll
        for (int r = 0; r < NROW; ++r)
            ((float4*)part[wv][r])[c4] = acck[r];
        #pragma unroll
        for (int qi = 0; qi < TQ; ++qi)
            ((float4*)part[wv][NROW + qi])[c4] = accq[qi];
    }
    __syncthreads();

    // ---- scores: 12 (query, offset) pairs; 8-way combine folded in ----
    for (int p = wv; p < TQ * 3; p += 8) {
        int qi = p / 3, jj = p - qi * 3;
        int j = i0 + qi - 1 + jj;          // global key index
        float sum;
        if (j >= 0 && j < LL) {            // wave-uniform branch
            int r = qi + jj;
            sum = 0.0f;
            #pragma unroll
            for (int u = 0; u < 2; ++u) {
                int d = lane + u * 64;
                float qv = 0.f, kv = 0.f;
                #pragma unroll
                for (int sp = 0; sp < NSP; ++sp) {
                    qv += part[sp][NROW + qi][d];
                    kv += part[sp][r][d];
                }
                sum += fast_tanh(qv + kv + shbh[d]) * shwa[d];
            }
            #pragma unroll
            for (int off = 32; off > 0; off >>= 1)
                sum += __shfl_xor(sum, off, 64);
        } else {
            sum = -1e30f;
        }
        if (lane == 0) score[p] = sum;
    }
    __syncthreads();

    // ---- output: per-thread redundant 3-term softmax + weighted sum ----
    {
        int c = t & 127;
        int qi = t >> 7;                   // 0..3 (wave-uniform)
        float s0 = score[qi * 3 + 0], s1 = score[qi * 3 + 1], s2 = score[qi * 3 + 2];
        float m = fmaxf(s0, fmaxf(s1, s2));
        float e0 = (s0 > -1e29f) ? __expf(s0 - m) : 0.0f;
        float e1 = (s1 > -1e29f) ? __expf(s1 - m) : 0.0f;
        float e2 = (s2 > -1e29f) ? __expf(s2 - m) : 0.0f;
        float inv = 1.0f / (e0 + e1 + e2 + EPSV);
        float v = (e0 * xs[qi][c] + e1 * xs[qi + 1][c] + e2 * xs[qi + 2][c]) * inv;
        out[(size_t)(b * LL + i0 + qi) * DD + c] = v;
    }
}

extern "C" void kernel_launch(void* const* d_in, const int* in_sizes, int n_in,
                              void* d_out, int out_size, void* d_ws, size_t ws_size,
                              hipStream_t stream) {
    const float* x  = (const float*)d_in[0];
    const float* Wt = (const float*)d_in[1];
    const float* Wx = (const float*)d_in[2];
    const float* Wa = (const float*)d_in[3];
    const float* bh = (const float*)d_in[4];
    const float* ba = (const float*)d_in[5];
    float* out = (float*)d_out;

    dim3 grid(BB * (LL / TQ));   // 512 blocks -> 2 blocks/CU
    additive_emission_kernel<<<grid, 512, 0, stream>>>(x, Wt, Wx, Wa, bh, ba, out);
}

// Round 5
// 69.452 us; speedup vs baseline: 1.0319x; 1.0319x over previous
//
#include <hip/hip_runtime.h>
#include <math.h>

#define BB 4
#define LL 512
#define DD 128
#define TQ 4                 // queries per block
#define NROW (TQ + 2)        // 6 staged x rows
#define NACC (NROW + TQ)     // 10 GEMV outputs: 0..5 = k rows, 6..9 = q rows
#define NS 4                 // split-K ways
#define KPT (DD / NS)        // 32 K-values per thread
#define EPSV 1e-8f

__device__ __forceinline__ float fast_tanh(float v) {
    float e = __expf(2.0f * v);
    return 1.0f - 2.0f / (e + 1.0f);
}

__global__ __launch_bounds__(512, 4) void additive_emission_kernel(
    const float* __restrict__ x,   // [B,L,D]
    const float* __restrict__ Wt,  // [D,D] row-major [d_in][d_out]
    const float* __restrict__ Wx,  // [D,D]
    const float* __restrict__ Wa,  // [D]
    const float* __restrict__ bh,  // [D]
    const float* __restrict__ ba,  // [1]  (cancels in softmax -> unused)
    float* __restrict__ out)       // [B,L,D]
{
    __shared__ float xs[NROW][DD];
    __shared__ float part[NS][NACC][DD];
    __shared__ float shbh[DD];
    __shared__ float shwa[DD];
    __shared__ float score[TQ * 3];

    const int t = threadIdx.x;
    const int c = t & 127;            // output column
    const int s = t >> 7;             // split-K slice 0..3 (wave-uniform)
    const int dp0 = s * KPT;
    const int b = blockIdx.x >> 7;    // 128 tiles per batch
    const int tile = blockIdx.x & 127;
    const int i0 = tile * TQ;
    const int jlo = i0 - 1;

    // ---- issue ALL weight loads first; latency overlaps staging+barrier ----
    // (64 lanes read consecutive c -> each load is a coalesced 256B transaction)
    float wT[KPT], wX[KPT];
    {
        const float* __restrict__ wtp = Wt + (size_t)dp0 * DD + c;
        const float* __restrict__ wxp = Wx + (size_t)dp0 * DD + c;
        #pragma unroll
        for (int k = 0; k < KPT; ++k) {
            wT[k] = wtp[(size_t)k * DD];
            wX[k] = wxp[(size_t)k * DD];
        }
    }

    if (t < DD) { shbh[t] = bh[t]; shwa[t] = Wa[t]; }
    if (t < NROW * (DD / 4)) {        // 192 threads stage 6 x rows as float4
        int r = t >> 5, c4 = t & 31;
        int j = jlo + r;
        float4 v = make_float4(0.f, 0.f, 0.f, 0.f);
        if (j >= 0 && j < LL)
            v = ((const float4*)x)[(size_t)(b * LL + j) * (DD / 4) + c4];
        ((float4*)xs[r])[c4] = v;
    }
    __syncthreads();

    // ---- GEMV: LDS-broadcast x  ×  register weights ----
    float acc[NACC];
    #pragma unroll
    for (int r = 0; r < NACC; ++r) acc[r] = 0.f;

    #pragma unroll
    for (int ch = 0; ch < KPT / 4; ++ch) {
        const int kk = ch * 4;
        float xvv[NROW][4];
        #pragma unroll
        for (int r = 0; r < NROW; ++r) {
            float4 v = ((const float4*)xs[r])[(dp0 + kk) >> 2]; // wave-uniform broadcast
            xvv[r][0] = v.x; xvv[r][1] = v.y; xvv[r][2] = v.z; xvv[r][3] = v.w;
        }
        #pragma unroll
        for (int i = 0; i < 4; ++i) {
            float wx = wX[kk + i];
            float wt = wT[kk + i];
            #pragma unroll
            for (int r = 0; r < NROW; ++r)
                acc[r] += xvv[r][i] * wx;                 // k, 6 rows
            #pragma unroll
            for (int qi = 0; qi < TQ; ++qi)
                acc[NROW + qi] += xvv[qi + 1][i] * wt;    // q, 4 rows
        }
    }
    #pragma unroll
    for (int r = 0; r < NACC; ++r) part[s][r][c] = acc[r];
    __syncthreads();

    // ---- scores: 12 (query, offset) pairs; split-K combine folded in ----
    const int wv = t >> 6;
    const int lane = t & 63;
    for (int p = wv; p < TQ * 3; p += 8) {
        int qi = p / 3, jj = p - qi * 3;
        int j = i0 + qi - 1 + jj;          // global key index
        float sum;
        if (j >= 0 && j < LL) {            // wave-uniform branch
            int r = qi + jj;
            sum = 0.0f;
            #pragma unroll
            for (int u = 0; u < 2; ++u) {
                int d = lane + u * 64;
                float qv = part[0][NROW + qi][d] + part[1][NROW + qi][d]
                         + part[2][NROW + qi][d] + part[3][NROW + qi][d];
                float kv = part[0][r][d] + part[1][r][d]
                         + part[2][r][d] + part[3][r][d];
                sum += fast_tanh(qv + kv + shbh[d]) * shwa[d];
            }
            #pragma unroll
            for (int off = 32; off > 0; off >>= 1)
                sum += __shfl_xor(sum, off, 64);
        } else {
            sum = -1e30f;
        }
        if (lane == 0) score[p] = sum;
    }
    __syncthreads();

    // ---- output: per-thread redundant 3-term softmax + weighted sum ----
    {
        int qi = t >> 7;                   // 0..3 (wave-uniform)
        float s0 = score[qi * 3 + 0], s1 = score[qi * 3 + 1], s2 = score[qi * 3 + 2];
        float m = fmaxf(s0, fmaxf(s1, s2));
        float e0 = (s0 > -1e29f) ? __expf(s0 - m) : 0.0f;
        float e1 = (s1 > -1e29f) ? __expf(s1 - m) : 0.0f;
        float e2 = (s2 > -1e29f) ? __expf(s2 - m) : 0.0f;
        float inv = 1.0f / (e0 + e1 + e2 + EPSV);
        float v = (e0 * xs[qi][c] + e1 * xs[qi + 1][c] + e2 * xs[qi + 2][c]) * inv;
        out[(size_t)(b * LL + i0 + qi) * DD + c] = v;
    }
}

extern "C" void kernel_launch(void* const* d_in, const int* in_sizes, int n_in,
                              void* d_out, int out_size, void* d_ws, size_t ws_size,
                              hipStream_t stream) {
    const float* x  = (const float*)d_in[0];
    const float* Wt = (const float*)d_in[1];
    const float* Wx = (const float*)d_in[2];
    const float* Wa = (const float*)d_in[3];
    const float* bh = (const float*)d_in[4];
    const float* ba = (const float*)d_in[5];
    float* out = (float*)d_out;

    dim3 grid(BB * (LL / TQ));   // 512 blocks -> 2 blocks/CU
    additive_emission_kernel<<<grid, 512, 0, stream>>>(x, Wt, Wx, Wa, bh, ba, out);
}